// Round 7
// baseline (92.627 us; speedup 1.0000x reference)
//
#include <hip/hip_runtime.h>
#include <hip/hip_bf16.h>

// ---------------------------------------------------------------------------
// Fused attention: x@Wqkv -> q,k,v ; flash split-KV attention over
// concat(past_k, k_new) ; combine ; @Wproj -> out.
// B=2, N=256, DIM=1024, H=16, D=64, L=8192, total keys 8448 = 132 x 64.
// R7: NSPLIT=24 (768 blocks = 3 blocks/CU for phase diversity; needs VGPR<=85
// for 6 waves/SIMD -- do NOT add register pressure), setprio around MFMA
// clusters (T5), defer-max rescale skip with THR=8 in exp2 domain (T13).
// Keeps R6: 8-wave/512-thread blocks, 32 q/wave, dbuf LDS 1 barrier/step,
// cvt_pk staging, swapped-QK in-register softmax, sigma-permuted PV.
// ---------------------------------------------------------------------------

#define BB 2
#define NH 16
#define NQ 256
#define HD 64
#define DIMC 1024
#define LPAST 8192
#define TOTK 8448
#define NSPLIT 24
// 132 steps of 64 keys: splits 0..11 take 6 steps, 12..23 take 5.
// Steps 128..131 (inside split 23) read knew/vnew; selected per step.

typedef __attribute__((ext_vector_type(8))) short short8;
typedef __attribute__((ext_vector_type(4))) float f32x4;
typedef __attribute__((ext_vector_type(4))) int int4v;

#define DEVI static __device__ __forceinline__

DEVI float exp2g(float x) { return __builtin_amdgcn_exp2f(x); }  // v_exp_f32

DEVI int cvtpk(float lo, float hi) {     // dword = {bf16(lo), bf16(hi)}
  int r;
  asm("v_cvt_pk_bf16_f32 %0, %1, %2" : "=v"(r) : "v"(lo), "v"(hi));
  return r;
}
DEVI short f2bf(float f) {               // scalar f32 -> bf16 (RNE)
  union { float f; unsigned u; } v; v.f = f;
  unsigned r = v.u + 0x7FFFu + ((v.u >> 16) & 1u);
  return (short)(r >> 16);
}

// ---------------------------------------------------------------------------
// Generic 64x64-tile bf16 MFMA GEMM, f32 inputs converted during staging.
// MODE 0: Cout[row*Nn+col] = acc + bias[col]
// MODE 1: scatter into q (bf16, *0.125*log2e), k_new, v_new  [B,H,N,D]
// ---------------------------------------------------------------------------
template<int MODE>
__global__ __launch_bounds__(256, 2) void gemm_k(
    const float* __restrict__ A, const float* __restrict__ Bm,
    const float* __restrict__ bias, float* __restrict__ Cout,
    short* __restrict__ qbuf, float* __restrict__ knew, float* __restrict__ vnew,
    int M, int Nn, int K)
{
  __shared__ alignas(16) short As[64][72];   // [m][k] bf16, +8 pad
  __shared__ alignas(16) short Bs[64][72];   // [n][k] bf16 (B transposed)
  const int tid = threadIdx.x;
  const int lane = tid & 63, wave = tid >> 6;
  const int nblk = Nn >> 6;
  const int bi = blockIdx.x / nblk, bj = blockIdx.x % nblk;
  const int wm = wave >> 1, wn = wave & 1;
  const int g = lane >> 4, l16 = lane & 15;
  f32x4 acc[2][2] = {};
  const int r = tid >> 2, q4 = (tid & 3) << 4;

  for (int k0 = 0; k0 < K; k0 += 64) {
    const float* pa = A + (size_t)(bi * 64 + r) * K + (k0 + q4);
    float4 a0 = ((const float4*)pa)[0];
    float4 a1 = ((const float4*)pa)[1];
    float4 a2 = ((const float4*)pa)[2];
    float4 a3 = ((const float4*)pa)[3];
    const float* pb = Bm + (size_t)(k0 + r) * Nn + (bj * 64 + q4);
    float4 b0 = ((const float4*)pb)[0];
    float4 b1 = ((const float4*)pb)[1];
    float4 b2 = ((const float4*)pb)[2];
    float4 b3 = ((const float4*)pb)[3];
    __syncthreads();
    {
      int4v p0 = {cvtpk(a0.x,a0.y), cvtpk(a0.z,a0.w), cvtpk(a1.x,a1.y), cvtpk(a1.z,a1.w)};
      int4v p1 = {cvtpk(a2.x,a2.y), cvtpk(a2.z,a2.w), cvtpk(a3.x,a3.y), cvtpk(a3.z,a3.w)};
      *(int4v*)&As[r][q4]     = p0;
      *(int4v*)&As[r][q4 + 8] = p1;
    }
    Bs[q4+ 0][r] = f2bf(b0.x); Bs[q4+ 1][r] = f2bf(b0.y);
    Bs[q4+ 2][r] = f2bf(b0.z); Bs[q4+ 3][r] = f2bf(b0.w);
    Bs[q4+ 4][r] = f2bf(b1.x); Bs[q4+ 5][r] = f2bf(b1.y);
    Bs[q4+ 6][r] = f2bf(b1.z); Bs[q4+ 7][r] = f2bf(b1.w);
    Bs[q4+ 8][r] = f2bf(b2.x); Bs[q4+ 9][r] = f2bf(b2.y);
    Bs[q4+10][r] = f2bf(b2.z); Bs[q4+11][r] = f2bf(b2.w);
    Bs[q4+12][r] = f2bf(b3.x); Bs[q4+13][r] = f2bf(b3.y);
    Bs[q4+14][r] = f2bf(b3.z); Bs[q4+15][r] = f2bf(b3.w);
    __syncthreads();
    #pragma unroll
    for (int kf = 0; kf < 2; ++kf) {
      short8 af[2], bfv[2];
      #pragma unroll
      for (int mt = 0; mt < 2; ++mt)
        af[mt] = *(const short8*)&As[wm*32 + mt*16 + l16][kf*32 + g*8];
      #pragma unroll
      for (int nt = 0; nt < 2; ++nt)
        bfv[nt] = *(const short8*)&Bs[wn*32 + nt*16 + l16][kf*32 + g*8];
      #pragma unroll
      for (int mt = 0; mt < 2; ++mt)
        #pragma unroll
        for (int nt = 0; nt < 2; ++nt)
          acc[mt][nt] = __builtin_amdgcn_mfma_f32_16x16x32_bf16(
              af[mt], bfv[nt], acc[mt][nt], 0, 0, 0);
    }
  }

  #pragma unroll
  for (int mt = 0; mt < 2; ++mt)
    #pragma unroll
    for (int nt = 0; nt < 2; ++nt)
      #pragma unroll
      for (int rg = 0; rg < 4; ++rg) {
        int row = bi*64 + wm*32 + mt*16 + g*4 + rg;
        int col = bj*64 + wn*32 + nt*16 + l16;
        float val = acc[mt][nt][rg] + bias[col];
        if (MODE == 0) {
          Cout[(size_t)row * Nn + col] = val;
        } else {
          int which = col >> 10, cc = col & 1023;
          int h = cc >> 6, d = cc & 63;
          int b = row >> 8, n = row & 255;
          size_t idx = (((size_t)(b*NH + h))*NQ + n)*HD + d;
          if (which == 0)      qbuf[idx] = f2bf(val * 0.180336878f); // 0.125*log2(e)
          else if (which == 1) knew[idx] = val;
          else                 vnew[idx] = val;
        }
      }
}

// ---------------------------------------------------------------------------
// Flash attention, split-KV, swapped-QK in-register softmax (exp2 domain).
// Grid: (B*H)*NSPLIT blocks, 512 threads = 8 waves x 32 queries.
// Double-buffered K/V LDS, 1 barrier per 64-key step.
// P lands directly in PV A-fragment layout via key permutation
//   sigma(g,j,kk) = 32kk + 16*(j>>2) + 4g + (j&3),
// matched on the B side by reading Vt[d][sigma] (transposed V in LDS).
// ---------------------------------------------------------------------------
__global__ __launch_bounds__(512, 2) void attn_k(
    const short* __restrict__ qbuf, const float* __restrict__ pastk,
    const float* __restrict__ pastv, const float* __restrict__ knew,
    const float* __restrict__ vnew, float* __restrict__ opart,
    float* __restrict__ mbuf, float* __restrict__ lbuf)
{
  __shared__ alignas(16) short Kt[2][64][72];   // [buf][key][d]
  __shared__ alignas(16) short Vt[2][64][70];   // [buf][d][key], 35-dword stride
  const int tid = threadIdx.x;
  const int lane = tid & 63, wave = tid >> 6;      // wave 0..7
  const int g = lane >> 4, l16 = lane & 15;
  const int s = blockIdx.x % NSPLIT, bh = blockIdx.x / NSPLIT;
  const int kr = tid >> 3, q8 = (tid & 7) << 3;    // K staging: 1 key x 8 d
  const int vp = tid >> 4, d4 = (tid & 15) << 2;   // V staging: keys 2vp,2vp+1 x 4 d

  // Q fragments (B-operand of S^T): lane holds Q[q=qt*16+l16][d=half*32+g*8..+7]
  short8 qf[2][2];
  #pragma unroll
  for (int qt = 0; qt < 2; ++qt)
    #pragma unroll
    for (int half = 0; half < 2; ++half)
      qf[qt][half] = *(const short8*)(qbuf +
          ((size_t)bh*NQ + wave*32 + qt*16 + l16)*HD + half*32 + g*8);

  f32x4 acc[2][4] = {};     // acc[qt][dt]: q = qt*16+g*4+rg, d = dt*16+l16
  float m_s[2], l_s[2];
  #pragma unroll
  for (int qt = 0; qt < 2; ++qt) { m_s[qt] = -INFINITY; l_s[qt] = 0.f; }

  const int first  = (s < 12) ? 6*s : 5*s + 12;
  const int nsteps = (s < 12) ? 6 : 5;

  float4 ka[2], va, vc;
  auto load = [&](int step) {
    // step 0..127 -> past KV; 128..131 -> new KV (step-uniform branch)
    const float* kp = (step < 128)
        ? pastk + ((size_t)bh*LPAST + step*64 + kr)*HD + q8
        : knew  + ((size_t)bh*NQ + (step - 128)*64 + kr)*HD + q8;
    ka[0] = ((const float4*)kp)[0];
    ka[1] = ((const float4*)kp)[1];
    const float* vq = (step < 128)
        ? pastv + ((size_t)bh*LPAST + step*64 + 2*vp)*HD + d4
        : vnew  + ((size_t)bh*NQ + (step - 128)*64 + 2*vp)*HD + d4;
    va = *(const float4*)vq;
    vc = *(const float4*)(vq + HD);
  };
  auto stage = [&](int b) {
    const float* kf32 = (const float*)ka;
    int4v p = {cvtpk(kf32[0],kf32[1]), cvtpk(kf32[2],kf32[3]),
               cvtpk(kf32[4],kf32[5]), cvtpk(kf32[6],kf32[7])};
    *(int4v*)&Kt[b][kr][q8] = p;
    const float* af = (const float*)&va;
    const float* cf = (const float*)&vc;
    #pragma unroll
    for (int j = 0; j < 4; ++j)
      *(int*)&Vt[b][d4 + j][2*vp] = cvtpk(af[j], cf[j]);  // lo=key 2vp, hi=2vp+1
  };

  load(first);
  stage(0);
  if (nsteps > 1) load(first + 1);
  __syncthreads();

  for (int it = 0; it < nsteps; ++it) {
    const int cur = it & 1;

    short8 pa[2][2];
    #pragma unroll
    for (int qt = 0; qt < 2; ++qt) {
      f32x4 sv[4];
      __builtin_amdgcn_s_setprio(1);
      #pragma unroll
      for (int kt = 0; kt < 4; ++kt) {
        // K fragment reloaded per qt to keep live range at 8 regs
        short8 k0 = *(const short8*)&Kt[cur][kt*16 + l16][g*8];
        short8 k1 = *(const short8*)&Kt[cur][kt*16 + l16][32 + g*8];
        f32x4 z = {0.f, 0.f, 0.f, 0.f};
        z = __builtin_amdgcn_mfma_f32_16x16x32_bf16(k0, qf[qt][0], z, 0,0,0);
        sv[kt] = __builtin_amdgcn_mfma_f32_16x16x32_bf16(k1, qf[qt][1], z, 0,0,0);
      }
      __builtin_amdgcn_s_setprio(0);
      float mx = sv[0][0];
      #pragma unroll
      for (int kt = 0; kt < 4; ++kt)
        #pragma unroll
        for (int rg = 0; rg < 4; ++rg) mx = fmaxf(mx, sv[kt][rg]);
      mx = fmaxf(mx, __shfl_xor(mx, 16));
      mx = fmaxf(mx, __shfl_xor(mx, 32));
      // T13 defer-max: only rescale when some query's max grew past THR=8
      // (exp2 domain; P bounded by 2^8, safe in bf16/f32).
      if (!__all(mx <= m_s[qt] + 8.f)) {
        float m_new = fmaxf(m_s[qt], mx);
        float al = exp2g(m_s[qt] - m_new);
        l_s[qt] *= al;
        #pragma unroll
        for (int rg = 0; rg < 4; ++rg) {
          float a = __shfl(al, g*4 + rg);
          #pragma unroll
          for (int dt = 0; dt < 4; ++dt) acc[qt][dt][rg] *= a;
        }
        m_s[qt] = m_new;
      }
      float ss = 0.f;
      #pragma unroll
      for (int kt = 0; kt < 4; ++kt)
        #pragma unroll
        for (int rg = 0; rg < 4; ++rg) {
          float p = exp2g(sv[kt][rg] - m_s[qt]);
          sv[kt][rg] = p; ss += p;
        }
      ss += __shfl_xor(ss, 16);
      ss += __shfl_xor(ss, 32);
      l_s[qt] += ss;
      int4v w0 = {cvtpk(sv[0][0],sv[0][1]), cvtpk(sv[0][2],sv[0][3]),
                  cvtpk(sv[1][0],sv[1][1]), cvtpk(sv[1][2],sv[1][3])};
      int4v w1 = {cvtpk(sv[2][0],sv[2][1]), cvtpk(sv[2][2],sv[2][3]),
                  cvtpk(sv[3][0],sv[3][1]), cvtpk(sv[3][2],sv[3][3])};
      pa[qt][0] = __builtin_bit_cast(short8, w0);
      pa[qt][1] = __builtin_bit_cast(short8, w1);
    }

    // PV: B-frag slot j <- Vt[d][32kk + 16*(j>>2) + 4g + (j&3)]
    __builtin_amdgcn_s_setprio(1);
    #pragma unroll
    for (int kk = 0; kk < 2; ++kk) {
      #pragma unroll
      for (int dt = 0; dt < 4; ++dt) {
        const short* vrow = &Vt[cur][dt*16 + l16][kk*32 + 4*g];
        int i0 = *(const int*)(vrow);
        int i1 = *(const int*)(vrow + 2);
        int i2 = *(const int*)(vrow + 16);
        int i3 = *(const int*)(vrow + 18);
        int4v iv = {i0, i1, i2, i3};
        short8 vf = __builtin_bit_cast(short8, iv);
        #pragma unroll
        for (int qt = 0; qt < 2; ++qt)
          acc[qt][dt] = __builtin_amdgcn_mfma_f32_16x16x32_bf16(
              pa[qt][kk], vf, acc[qt][dt], 0,0,0);
      }
    }
    __builtin_amdgcn_s_setprio(0);

    if (it + 1 < nsteps) {
      stage(1 - cur);                       // write NEXT step's tile (other buffer)
      if (it + 2 < nsteps) load(first + it + 2);
      __syncthreads();
    }
  }

  // Write partials
  size_t pbase = ((size_t)(bh * NSPLIT + s)) * NQ;
  #pragma unroll
  for (int qt = 0; qt < 2; ++qt)
    #pragma unroll
    for (int dt = 0; dt < 4; ++dt)
      #pragma unroll
      for (int rg = 0; rg < 4; ++rg) {
        int row = wave*32 + qt*16 + g*4 + rg;
        int col = dt*16 + l16;
        opart[(pbase + row)*HD + col] = acc[qt][dt][rg];
      }
  if (g == 0) {
    #pragma unroll
    for (int qt = 0; qt < 2; ++qt) {
      int q = wave*32 + qt*16 + l16;
      mbuf[pbase + q] = m_s[qt];
      lbuf[pbase + q] = l_s[qt];
    }
  }
}

// ---------------------------------------------------------------------------
// Combine NSPLIT partials per (b,h,n); write attn output [B,N,DIM] f32
// ---------------------------------------------------------------------------
__global__ __launch_bounds__(256) void combine_k(
    const float* __restrict__ opart, const float* __restrict__ mbuf,
    const float* __restrict__ lbuf, float* __restrict__ attnout)
{
  const int lane = threadIdx.x & 63, wave = threadIdx.x >> 6;
  const int rid = blockIdx.x * 4 + wave;   // 0 .. B*H*N-1
  const int bh = rid >> 8, n = rid & 255;
  const int b = bh >> 4, h = bh & 15;
  float M = -INFINITY;
  float ms[NSPLIT], ls[NSPLIT];
  #pragma unroll
  for (int s = 0; s < NSPLIT; ++s) {
    size_t base = ((size_t)(bh * NSPLIT + s)) * NQ + n;
    ms[s] = mbuf[base]; ls[s] = lbuf[base];
    M = fmaxf(M, ms[s]);
  }
  float denom = 0.f, o = 0.f;
  #pragma unroll
  for (int s = 0; s < NSPLIT; ++s) {
    float w = exp2g(ms[s] - M);
    denom += w * ls[s];
    o += w * opart[(((size_t)(bh * NSPLIT + s)) * NQ + n) * HD + lane];
  }
  attnout[((size_t)(b * NQ + n)) * DIMC + h * HD + lane] = o / denom;
}

// ---------------------------------------------------------------------------
extern "C" void kernel_launch(void* const* d_in, const int* in_sizes, int n_in,
                              void* d_out, int out_size, void* d_ws, size_t ws_size,
                              hipStream_t stream)
{
  const float* x     = (const float*)d_in[0];
  const float* pastk = (const float*)d_in[1];
  const float* pastv = (const float*)d_in[2];
  const float* wqkv  = (const float*)d_in[3];
  const float* bqkv  = (const float*)d_in[4];
  const float* wproj = (const float*)d_in[5];
  const float* bproj = (const float*)d_in[6];
  float* out = (float*)d_out;
  char* ws = (char*)d_ws;

  size_t off = 0;
  short* qbuf   = (short*)(ws + off); off += (size_t)BB*NH*NQ*HD*2;          // 1MB
  float* knew   = (float*)(ws + off); off += (size_t)BB*NH*NQ*HD*4;          // 2MB
  float* vnew   = (float*)(ws + off); off += (size_t)BB*NH*NQ*HD*4;          // 2MB
  float* opart  = (float*)(ws + off); off += (size_t)BB*NH*NSPLIT*NQ*HD*4;   // 48MB
  float* mbuf   = (float*)(ws + off); off += (size_t)BB*NH*NSPLIT*NQ*4;      // 768KB
  float* lbuf   = (float*)(ws + off); off += (size_t)BB*NH*NSPLIT*NQ*4;      // 768KB
  float* attnout= (float*)(ws + off); off += (size_t)BB*NQ*DIMC*4;           // 2MB

  // 1) QKV projection: [512,1024] x [1024,3072]
  gemm_k<1><<<(512/64)*(3072/64), 256, 0, stream>>>(
      x, wqkv, bqkv, nullptr, qbuf, knew, vnew, 512, 3072, 1024);
  // 2) split-KV flash attention
  attn_k<<<BB*NH*NSPLIT, 512, 0, stream>>>(
      qbuf, pastk, pastv, knew, vnew, opart, mbuf, lbuf);
  // 3) combine partials
  combine_k<<<BB*NH*NQ/4, 256, 0, stream>>>(opart, mbuf, lbuf, attnout);
  // 4) output projection: [512,1024] x [1024,1024]
  gemm_k<0><<<(512/64)*(1024/64), 256, 0, stream>>>(
      attnout, wproj, bproj, out, nullptr, nullptr, nullptr, 512, 1024, 1024);
}

// Round 8
// 89.393 us; speedup vs baseline: 1.0362x; 1.0362x over previous
//
#include <hip/hip_runtime.h>
#include <hip/hip_bf16.h>

// ---------------------------------------------------------------------------
// Fused attention: x@Wqkv -> q,k,v ; flash split-KV attention over
// concat(past_k, k_new) ; combine ; @Wproj -> out.
// B=2, N=256, DIM=1024, H=16, D=64, L=8192, total keys 8448 = 132 x 64.
// R8: 32x32x16 MFMA core (lane query = lane&31), XOR-swizzled conflict-free
// Kt/Vt (stride 64, col ^= (row&7)<<3 shorts), permuted V layout so the PV
// B-frag is ONE ds_read_b128, P packed in-register to match (sigma/pi pair).
// 8-wave/512-thread blocks, NSPLIT=16, dbuf LDS 1 barrier/step, cvt_pk,
// exp2-domain softmax, defer-max (THR=8), setprio on MFMA clusters.
// ---------------------------------------------------------------------------

#define BB 2
#define NH 16
#define NQ 256
#define HD 64
#define DIMC 1024
#define LPAST 8192
#define TOTK 8448
#define NSPLIT 16
// 132 steps of 64 keys: splits 0..3 take 9 steps, 4..15 take 8.
// Steps 128..131 (inside split 15) read knew/vnew; selected per step.

typedef __attribute__((ext_vector_type(8))) short short8;
typedef __attribute__((ext_vector_type(4))) float f32x4;
typedef __attribute__((ext_vector_type(16))) float f32x16;
typedef __attribute__((ext_vector_type(4))) int int4v;

#define DEVI static __device__ __forceinline__

DEVI float exp2g(float x) { return __builtin_amdgcn_exp2f(x); }  // v_exp_f32

DEVI int cvtpk(float lo, float hi) {     // dword = {bf16(lo), bf16(hi)}
  int r;
  asm("v_cvt_pk_bf16_f32 %0, %1, %2" : "=v"(r) : "v"(lo), "v"(hi));
  return r;
}
DEVI short f2bf(float f) {               // scalar f32 -> bf16 (RNE)
  union { float f; unsigned u; } v; v.f = f;
  unsigned r = v.u + 0x7FFFu + ((v.u >> 16) & 1u);
  return (short)(r >> 16);
}

// ---------------------------------------------------------------------------
// Generic 64x64-tile bf16 MFMA GEMM, f32 inputs converted during staging.
// MODE 0: Cout[row*Nn+col] = acc + bias[col]
// MODE 1: scatter into q (bf16, *0.125*log2e), k_new, v_new  [B,H,N,D]
// ---------------------------------------------------------------------------
template<int MODE>
__global__ __launch_bounds__(256, 2) void gemm_k(
    const float* __restrict__ A, const float* __restrict__ Bm,
    const float* __restrict__ bias, float* __restrict__ Cout,
    short* __restrict__ qbuf, float* __restrict__ knew, float* __restrict__ vnew,
    int M, int Nn, int K)
{
  __shared__ alignas(16) short As[64][72];   // [m][k] bf16, +8 pad
  __shared__ alignas(16) short Bs[64][72];   // [n][k] bf16 (B transposed)
  const int tid = threadIdx.x;
  const int lane = tid & 63, wave = tid >> 6;
  const int nblk = Nn >> 6;
  const int bi = blockIdx.x / nblk, bj = blockIdx.x % nblk;
  const int wm = wave >> 1, wn = wave & 1;
  const int g = lane >> 4, l16 = lane & 15;
  f32x4 acc[2][2] = {};
  const int r = tid >> 2, q4 = (tid & 3) << 4;

  for (int k0 = 0; k0 < K; k0 += 64) {
    const float* pa = A + (size_t)(bi * 64 + r) * K + (k0 + q4);
    float4 a0 = ((const float4*)pa)[0];
    float4 a1 = ((const float4*)pa)[1];
    float4 a2 = ((const float4*)pa)[2];
    float4 a3 = ((const float4*)pa)[3];
    const float* pb = Bm + (size_t)(k0 + r) * Nn + (bj * 64 + q4);
    float4 b0 = ((const float4*)pb)[0];
    float4 b1 = ((const float4*)pb)[1];
    float4 b2 = ((const float4*)pb)[2];
    float4 b3 = ((const float4*)pb)[3];
    __syncthreads();
    {
      int4v p0 = {cvtpk(a0.x,a0.y), cvtpk(a0.z,a0.w), cvtpk(a1.x,a1.y), cvtpk(a1.z,a1.w)};
      int4v p1 = {cvtpk(a2.x,a2.y), cvtpk(a2.z,a2.w), cvtpk(a3.x,a3.y), cvtpk(a3.z,a3.w)};
      *(int4v*)&As[r][q4]     = p0;
      *(int4v*)&As[r][q4 + 8] = p1;
    }
    Bs[q4+ 0][r] = f2bf(b0.x); Bs[q4+ 1][r] = f2bf(b0.y);
    Bs[q4+ 2][r] = f2bf(b0.z); Bs[q4+ 3][r] = f2bf(b0.w);
    Bs[q4+ 4][r] = f2bf(b1.x); Bs[q4+ 5][r] = f2bf(b1.y);
    Bs[q4+ 6][r] = f2bf(b1.z); Bs[q4+ 7][r] = f2bf(b1.w);
    Bs[q4+ 8][r] = f2bf(b2.x); Bs[q4+ 9][r] = f2bf(b2.y);
    Bs[q4+10][r] = f2bf(b2.z); Bs[q4+11][r] = f2bf(b2.w);
    Bs[q4+12][r] = f2bf(b3.x); Bs[q4+13][r] = f2bf(b3.y);
    Bs[q4+14][r] = f2bf(b3.z); Bs[q4+15][r] = f2bf(b3.w);
    __syncthreads();
    #pragma unroll
    for (int kf = 0; kf < 2; ++kf) {
      short8 af[2], bfv[2];
      #pragma unroll
      for (int mt = 0; mt < 2; ++mt)
        af[mt] = *(const short8*)&As[wm*32 + mt*16 + l16][kf*32 + g*8];
      #pragma unroll
      for (int nt = 0; nt < 2; ++nt)
        bfv[nt] = *(const short8*)&Bs[wn*32 + nt*16 + l16][kf*32 + g*8];
      #pragma unroll
      for (int mt = 0; mt < 2; ++mt)
        #pragma unroll
        for (int nt = 0; nt < 2; ++nt)
          acc[mt][nt] = __builtin_amdgcn_mfma_f32_16x16x32_bf16(
              af[mt], bfv[nt], acc[mt][nt], 0, 0, 0);
    }
  }

  #pragma unroll
  for (int mt = 0; mt < 2; ++mt)
    #pragma unroll
    for (int nt = 0; nt < 2; ++nt)
      #pragma unroll
      for (int rg = 0; rg < 4; ++rg) {
        int row = bi*64 + wm*32 + mt*16 + g*4 + rg;
        int col = bj*64 + wn*32 + nt*16 + l16;
        float val = acc[mt][nt][rg] + bias[col];
        if (MODE == 0) {
          Cout[(size_t)row * Nn + col] = val;
        } else {
          int which = col >> 10, cc = col & 1023;
          int h = cc >> 6, d = cc & 63;
          int b = row >> 8, n = row & 255;
          size_t idx = (((size_t)(b*NH + h))*NQ + n)*HD + d;
          if (which == 0)      qbuf[idx] = f2bf(val * 0.180336878f); // 0.125*log2(e)
          else if (which == 1) knew[idx] = val;
          else                 vnew[idx] = val;
        }
      }
}

// ---------------------------------------------------------------------------
// Flash attention, split-KV, swapped-QK in-register softmax (exp2 domain).
// Grid: (B*H)*NSPLIT blocks, 512 threads = 8 waves x 32 queries.
// Per 64-key step: S^T = mfma32x32x16(K, Q): lane (h=lane>>5, c=lane&31)
// holds 32 scores for query c, keys key' = (r&3)+8*(r>>2)+4h (+32*kt).
// P packed so PV A-frag slot (kc, j=8h+j') maps key
//   sigma = 32*(kc>>1) + 16*(j>>2) + 8*(kc&1) + 4h + (j&3);
// V stored at Vt[d][pi(key)] with pi(32kt+16b+8a+4h+r) = 32kt+16a+8h+4b+r
// so pi(sigma) = 16*kc+8h+j  => PV B-frag is ONE b128 read.
// Both Kt/Vt XOR-swizzled: short-col ^= (row&7)<<3  => conflict-free b128.
// ---------------------------------------------------------------------------
__global__ __launch_bounds__(512, 2) void attn_k(
    const short* __restrict__ qbuf, const float* __restrict__ pastk,
    const float* __restrict__ pastv, const float* __restrict__ knew,
    const float* __restrict__ vnew, float* __restrict__ opart,
    float* __restrict__ mbuf, float* __restrict__ lbuf)
{
  __shared__ alignas(16) short Kt[2][64][64];   // [buf][key][d], swizzled
  __shared__ alignas(16) short Vt[2][64][64];   // [buf][d][pi(key)], swizzled
  const int tid = threadIdx.x;
  const int lane = tid & 63, wave = tid >> 6;      // wave 0..7
  const int h = lane >> 5, c = lane & 31;
  const int s = blockIdx.x & (NSPLIT - 1), bh = blockIdx.x / NSPLIT;
  const int kr = tid >> 3, kc8 = (tid & 7) << 3;   // K staging: key kr, d kc8..+7
  const int vp = tid >> 4, vd = tid & 15;          // V staging: keys 2vp,2vp+1; d=vd+16j
  const int vpi = ((vp>>4)<<5) | (((vp>>2)&1)<<4) | (((vp>>1)&1)<<3)
                | (((vp>>3)&1)<<2) | ((vp&1)<<1);  // pi(2*vp)
  const int vsw = vpi ^ ((vd & 7) << 3);           // swizzled V col (row&7 == vd&7)
  const int csw = (c & 7) << 3;                    // read-side swizzle term

  // Q fragments (B-operand): lane holds Q[q=c][d = 16*dk + 8h + 0..7]
  short8 qf[4];
  #pragma unroll
  for (int dk = 0; dk < 4; ++dk)
    qf[dk] = *(const short8*)(qbuf + ((size_t)bh*NQ + wave*32 + c)*HD + 16*dk + 8*h);

  f32x16 acc[2] = {};        // acc[dt]: O[q=(r&3)+8*(r>>2)+4h][d=32*dt+c]
  float m_s = -INFINITY, l_s = 0.f;

  const int first  = 8*s + (s < 4 ? s : 4);
  const int nsteps = 8 + (s < 4 ? 1 : 0);

  float kfl[8], vlo[4], vhi[4];
  auto load = [&](int step) {
    const float* kp = (step < 128)
        ? pastk + ((size_t)bh*LPAST + step*64 + kr)*HD + kc8
        : knew  + ((size_t)bh*NQ + (step - 128)*64 + kr)*HD + kc8;
    *(float4*)&kfl[0] = *(const float4*)kp;
    *(float4*)&kfl[4] = *(const float4*)(kp + 4);
    const float* vq = (step < 128)
        ? pastv + ((size_t)bh*LPAST + step*64 + 2*vp)*HD + vd
        : vnew  + ((size_t)bh*NQ + (step - 128)*64 + 2*vp)*HD + vd;
    #pragma unroll
    for (int j = 0; j < 4; ++j) { vlo[j] = vq[16*j]; vhi[j] = vq[HD + 16*j]; }
  };
  auto stage = [&](int b) {
    int4v kp4 = {cvtpk(kfl[0],kfl[1]), cvtpk(kfl[2],kfl[3]),
                 cvtpk(kfl[4],kfl[5]), cvtpk(kfl[6],kfl[7])};
    *(int4v*)&Kt[b][kr][kc8 ^ ((kr & 7) << 3)] = kp4;
    #pragma unroll
    for (int j = 0; j < 4; ++j)
      *(int*)&Vt[b][vd + 16*j][vsw] = cvtpk(vlo[j], vhi[j]);  // lo=2vp, hi=2vp+1
  };

  load(first);
  stage(0);
  if (nsteps > 1) load(first + 1);
  __syncthreads();

  for (int it = 0; it < nsteps; ++it) {
    const int cur = it & 1;

    // S^T = K * Q^T, two 32-key tiles
    f32x16 sv0 = {}, sv1 = {};
    __builtin_amdgcn_s_setprio(1);
    #pragma unroll
    for (int dk = 0; dk < 4; ++dk) {
      short8 k0 = *(const short8*)&Kt[cur][c][(16*dk + 8*h) ^ csw];
      sv0 = __builtin_amdgcn_mfma_f32_32x32x16_bf16(k0, qf[dk], sv0, 0,0,0);
    }
    #pragma unroll
    for (int dk = 0; dk < 4; ++dk) {
      short8 k1 = *(const short8*)&Kt[cur][32 + c][(16*dk + 8*h) ^ csw];
      sv1 = __builtin_amdgcn_mfma_f32_32x32x16_bf16(k1, qf[dk], sv1, 0,0,0);
    }
    __builtin_amdgcn_s_setprio(0);

    // online softmax for query c (32 scores in-lane + h-partner)
    float t16[16];
    #pragma unroll
    for (int r = 0; r < 16; ++r) t16[r] = fmaxf(sv0[r], sv1[r]);
    #pragma unroll
    for (int w = 8; w >= 1; w >>= 1)
      #pragma unroll
      for (int r = 0; r < w; ++r) t16[r] = fmaxf(t16[r], t16[r + w]);
    float mx = fmaxf(t16[0], __shfl_xor(t16[0], 32));

    if (!__all(mx <= m_s + 8.f)) {      // T13 defer-max, THR=8 (exp2 domain)
      float mn = fmaxf(m_s, mx);
      float al = exp2g(m_s - mn);
      l_s *= al;
      #pragma unroll
      for (int r = 0; r < 16; ++r) {
        float a = __shfl(al, (r&3) + 8*(r>>2) + 4*h);
        acc[0][r] *= a; acc[1][r] *= a;
      }
      m_s = mn;
    }
    float ss = 0.f;
    #pragma unroll
    for (int r = 0; r < 16; ++r) {
      float p0 = exp2g(sv0[r] - m_s); sv0[r] = p0;
      float p1 = exp2g(sv1[r] - m_s); sv1[r] = p1;
      ss += p0 + p1;
    }
    ss += __shfl_xor(ss, 32);
    l_s += ss;

    // pack P into PV A-frags (key permutation sigma)
    short8 pa[4];
    #pragma unroll
    for (int kc = 0; kc < 4; ++kc) {
      int4v w;
      #pragma unroll
      for (int jd = 0; jd < 4; ++jd) {
        int r0 = 8*(jd>>1) + 4*(kc&1) + 2*(jd&1);
        w[jd] = (kc < 2) ? cvtpk(sv0[r0], sv0[r0+1])
                         : cvtpk(sv1[r0], sv1[r0+1]);
      }
      pa[kc] = __builtin_bit_cast(short8, w);
    }

    // PV: one b128 per (kc, dt)
    __builtin_amdgcn_s_setprio(1);
    #pragma unroll
    for (int kc = 0; kc < 4; ++kc) {
      #pragma unroll
      for (int dt = 0; dt < 2; ++dt) {
        short8 vf = *(const short8*)&Vt[cur][32*dt + c][(16*kc + 8*h) ^ csw];
        acc[dt] = __builtin_amdgcn_mfma_f32_32x32x16_bf16(pa[kc], vf, acc[dt], 0,0,0);
      }
    }
    __builtin_amdgcn_s_setprio(0);

    if (it + 1 < nsteps) {
      stage(1 - cur);                       // write NEXT step's tile (other buffer)
      if (it + 2 < nsteps) load(first + it + 2);
      __syncthreads();
    }
  }

  // Write partials
  size_t pbase = ((size_t)(bh * NSPLIT + s)) * NQ;
  #pragma unroll
  for (int dt = 0; dt < 2; ++dt)
    #pragma unroll
    for (int r = 0; r < 16; ++r) {
      int row = wave*32 + (r&3) + 8*(r>>2) + 4*h;
      opart[(pbase + row)*HD + 32*dt + c] = acc[dt][r];
    }
  if (lane < 32) {
    mbuf[pbase + wave*32 + c] = m_s;
    lbuf[pbase + wave*32 + c] = l_s;
  }
}

// ---------------------------------------------------------------------------
// Combine NSPLIT partials per (b,h,n); write attn output [B,N,DIM] f32
// ---------------------------------------------------------------------------
__global__ __launch_bounds__(256) void combine_k(
    const float* __restrict__ opart, const float* __restrict__ mbuf,
    const float* __restrict__ lbuf, float* __restrict__ attnout)
{
  const int lane = threadIdx.x & 63, wave = threadIdx.x >> 6;
  const int rid = blockIdx.x * 4 + wave;   // 0 .. B*H*N-1
  const int bh = rid >> 8, n = rid & 255;
  const int b = bh >> 4, h = bh & 15;
  float M = -INFINITY;
  float ms[NSPLIT], ls[NSPLIT];
  #pragma unroll
  for (int s = 0; s < NSPLIT; ++s) {
    size_t base = ((size_t)(bh * NSPLIT + s)) * NQ + n;
    ms[s] = mbuf[base]; ls[s] = lbuf[base];
    M = fmaxf(M, ms[s]);
  }
  float denom = 0.f, o = 0.f;
  #pragma unroll
  for (int s = 0; s < NSPLIT; ++s) {
    float w = exp2g(ms[s] - M);
    denom += w * ls[s];
    o += w * opart[(((size_t)(bh * NSPLIT + s)) * NQ + n) * HD + lane];
  }
  attnout[((size_t)(b * NQ + n)) * DIMC + h * HD + lane] = o / denom;
}

// ---------------------------------------------------------------------------
extern "C" void kernel_launch(void* const* d_in, const int* in_sizes, int n_in,
                              void* d_out, int out_size, void* d_ws, size_t ws_size,
                              hipStream_t stream)
{
  const float* x     = (const float*)d_in[0];
  const float* pastk = (const float*)d_in[1];
  const float* pastv = (const float*)d_in[2];
  const float* wqkv  = (const float*)d_in[3];
  const float* bqkv  = (const float*)d_in[4];
  const float* wproj = (const float*)d_in[5];
  const float* bproj = (const float*)d_in[6];
  float* out = (float*)d_out;
  char* ws = (char*)d_ws;

  size_t off = 0;
  short* qbuf   = (short*)(ws + off); off += (size_t)BB*NH*NQ*HD*2;          // 1MB
  float* knew   = (float*)(ws + off); off += (size_t)BB*NH*NQ*HD*4;          // 2MB
  float* vnew   = (float*)(ws + off); off += (size_t)BB*NH*NQ*HD*4;          // 2MB
  float* opart  = (float*)(ws + off); off += (size_t)BB*NH*NSPLIT*NQ*HD*4;   // 32MB
  float* mbuf   = (float*)(ws + off); off += (size_t)BB*NH*NSPLIT*NQ*4;      // 512KB
  float* lbuf   = (float*)(ws + off); off += (size_t)BB*NH*NSPLIT*NQ*4;      // 512KB
  float* attnout= (float*)(ws + off); off += (size_t)BB*NQ*DIMC*4;           // 2MB

  // 1) QKV projection: [512,1024] x [1024,3072]
  gemm_k<1><<<(512/64)*(3072/64), 256, 0, stream>>>(
      x, wqkv, bqkv, nullptr, qbuf, knew, vnew, 512, 3072, 1024);
  // 2) split-KV flash attention
  attn_k<<<BB*NH*NSPLIT, 512, 0, stream>>>(
      qbuf, pastk, pastv, knew, vnew, opart, mbuf, lbuf);
  // 3) combine partials
  combine_k<<<BB*NH*NQ/4, 256, 0, stream>>>(opart, mbuf, lbuf, attnout);
  // 4) output projection: [512,1024] x [1024,1024]
  gemm_k<0><<<(512/64)*(1024/64), 256, 0, stream>>>(
      attnout, wproj, bproj, out, nullptr, nullptr, nullptr, 512, 1024, 1024);
}